// Round 1
// baseline (3000.886 us; speedup 1.0000x reference)
//
#include <hip/hip_runtime.h>

#define NN 50000
#define NE 800000
#define D 128
#define ED 64
#define IN_DIM 320
#define EPB 32   // edges per block

// ---------------- gather X tile into LDS (transposed: xt[k][e]) -------------
__device__ __forceinline__ void stage_x(
    float xt[IN_DIM][EPB], const int* sS, const int* sR,
    const float* __restrict__ nodes, const float* __restrict__ efeat,
    int e0, int tid)
{
  const int e = tid >> 3, j = tid & 7;           // 32 edges x 8 loaders
  const float* ns = nodes + (size_t)sS[e] * D;
  const float* nr = nodes + (size_t)sR[e] * D;
  const float* ef = efeat + (size_t)(e0 + e) * ED;
#pragma unroll
  for (int m = 0; m < 4; ++m) {
    float4 v = *(const float4*)(ns + j * 16 + m * 4);
    int k = j * 16 + m * 4;
    xt[k][e] = v.x; xt[k + 1][e] = v.y; xt[k + 2][e] = v.z; xt[k + 3][e] = v.w;
  }
#pragma unroll
  for (int m = 0; m < 4; ++m) {
    float4 v = *(const float4*)(nr + j * 16 + m * 4);
    int k = 128 + j * 16 + m * 4;
    xt[k][e] = v.x; xt[k + 1][e] = v.y; xt[k + 2][e] = v.z; xt[k + 3][e] = v.w;
  }
#pragma unroll
  for (int m = 0; m < 2; ++m) {
    float4 v = *(const float4*)(ef + j * 8 + m * 4);
    int k = 256 + j * 8 + m * 4;
    xt[k][e] = v.x; xt[k + 1][e] = v.y; xt[k + 2][e] = v.z; xt[k + 3][e] = v.w;
  }
}

// ---------------- pass 1: logits + segment max ------------------------------
__global__ __launch_bounds__(256) void k_logits(
    const float* __restrict__ nodes,
    const int* __restrict__ senders, const int* __restrict__ receivers,
    const float* __restrict__ efeat,
    const float* __restrict__ W1, const float* __restrict__ b1,
    const float* __restrict__ gamma_, const float* __restrict__ beta_,
    const float* __restrict__ W2, const float* __restrict__ b2,
    float* __restrict__ logits, float* __restrict__ seg_max)
{
  __shared__ float xt[IN_DIM][EPB];
  __shared__ int sS[EPB], sR[EPB];
  __shared__ float cw1[4][16], cw2[4][16], cwd[4][16];
  const int tid = threadIdx.x;
  const int e0 = blockIdx.x * EPB;
  if (tid < EPB) { sS[tid] = senders[e0 + tid]; sR[tid] = receivers[e0 + tid]; }
  __syncthreads();
  stage_x(xt, sS, sR, nodes, efeat, e0, tid);
  __syncthreads();

  const int c = tid & 127;     // output column
  const int h = tid >> 7;      // which 16-edge half
  const float b1c = b1[c];

  float acc[16];
#pragma unroll
  for (int e = 0; e < 16; ++e) acc[e] = 0.f;

#pragma unroll 2
  for (int k = 0; k < IN_DIM; ++k) {
    float w = W1[k * D + c];
    const float4* xr = (const float4*)&xt[k][h * 16];
    float xv[16];
    *(float4*)&xv[0]  = xr[0];
    *(float4*)&xv[4]  = xr[1];
    *(float4*)&xv[8]  = xr[2];
    *(float4*)&xv[12] = xr[3];
#pragma unroll
    for (int e = 0; e < 16; ++e) acc[e] = fmaf(xv[e], w, acc[e]);
  }

  // ReLU then LN stats (sum, sumsq) across the 128 column-threads
  float hv[16], r1[16], r2[16];
#pragma unroll
  for (int e = 0; e < 16; ++e) {
    float v = fmaxf(acc[e] + b1c, 0.f);
    hv[e] = v; r1[e] = v; r2[e] = v * v;
  }
  for (int off = 1; off < 64; off <<= 1) {
#pragma unroll
    for (int e = 0; e < 16; ++e) {
      r1[e] += __shfl_xor(r1[e], off);
      r2[e] += __shfl_xor(r2[e], off);
    }
  }
  const int wid = tid >> 6, lane = tid & 63;
  if (lane == 0) {
#pragma unroll
    for (int e = 0; e < 16; ++e) { cw1[wid][e] = r1[e]; cw2[wid][e] = r2[e]; }
  }
  __syncthreads();

  const float gc = gamma_[c], bc = beta_[c], w2c = W2[c];
  float dv[16];
#pragma unroll
  for (int e = 0; e < 16; ++e) {
    float s  = cw1[2 * h][e] + cw1[2 * h + 1][e];
    float sq = cw2[2 * h][e] + cw2[2 * h + 1][e];
    float mu  = s * (1.f / 128.f);
    float var = fmaxf(sq * (1.f / 128.f) - mu * mu, 0.f);
    float rs  = rsqrtf(var + 1e-5f);
    float hn  = (hv[e] - mu) * rs * gc + bc;
    dv[e] = hn * w2c;
  }
  for (int off = 1; off < 64; off <<= 1) {
#pragma unroll
    for (int e = 0; e < 16; ++e) dv[e] += __shfl_xor(dv[e], off);
  }
  if (lane == 0) {
#pragma unroll
    for (int e = 0; e < 16; ++e) cwd[wid][e] = dv[e];
  }
  __syncthreads();
  if (tid < 32) {
    int hh = tid >> 4, ee = tid & 15;
    float d = cwd[2 * hh][ee] + cwd[2 * hh + 1][ee];
    float logit = fmaxf(d + b2[0], 0.f);
    int ge = e0 + hh * 16 + ee;
    logits[ge] = logit;
    // logits >= 0, so int-compare == float-compare; seg_max pre-zeroed
    atomicMax((int*)&seg_max[sR[hh * 16 + ee]], __float_as_int(logit));
  }
}

// ---------------- pass 2: exp + segment sum ---------------------------------
__global__ __launch_bounds__(256) void k_exp(
    const float* __restrict__ logits, const int* __restrict__ receivers,
    const float* __restrict__ seg_max, float* __restrict__ exp_l,
    float* __restrict__ seg_sum)
{
  int i = blockIdx.x * 256 + threadIdx.x;
  if (i < NE) {
    int r = receivers[i];
    float ex = expf(logits[i] - seg_max[r]);
    exp_l[i] = ex;
    atomicAdd(&seg_sum[r], ex);
  }
}

// ---------------- pass 3: queries * weight, scatter-add ---------------------
__global__ __launch_bounds__(256) void k_scatter(
    const float* __restrict__ nodes,
    const int* __restrict__ senders, const int* __restrict__ receivers,
    const float* __restrict__ efeat,
    const float* __restrict__ Wq, const float* __restrict__ bq,
    const float* __restrict__ exp_l, const float* __restrict__ seg_sum,
    float* __restrict__ accum)
{
  __shared__ float xt[IN_DIM][EPB];
  __shared__ int sS[EPB], sR[EPB];
  const int tid = threadIdx.x;
  const int e0 = blockIdx.x * EPB;
  if (tid < EPB) { sS[tid] = senders[e0 + tid]; sR[tid] = receivers[e0 + tid]; }
  __syncthreads();
  stage_x(xt, sS, sR, nodes, efeat, e0, tid);
  __syncthreads();

  const int c = tid & 127;
  const int h = tid >> 7;
  const float bqc = bq[c];

  float acc[16];
#pragma unroll
  for (int e = 0; e < 16; ++e) acc[e] = 0.f;

#pragma unroll 2
  for (int k = 0; k < IN_DIM; ++k) {
    float w = Wq[k * D + c];
    const float4* xr = (const float4*)&xt[k][h * 16];
    float xv[16];
    *(float4*)&xv[0]  = xr[0];
    *(float4*)&xv[4]  = xr[1];
    *(float4*)&xv[8]  = xr[2];
    *(float4*)&xv[12] = xr[3];
#pragma unroll
    for (int e = 0; e < 16; ++e) acc[e] = fmaf(xv[e], w, acc[e]);
  }

#pragma unroll
  for (int e = 0; e < 16; ++e) {
    int le = h * 16 + e;
    int ge = e0 + le;
    int r = sR[le];
    float w = exp_l[ge] / (seg_sum[r] + 1e-10f);
    atomicAdd(&accum[(size_t)r * D + c], (acc[e] + bqc) * w);
  }
}

// ---------------- pass 4: leaky relu ----------------------------------------
__global__ __launch_bounds__(256) void k_final(
    const float* __restrict__ accum, float* __restrict__ out)
{
  int i = blockIdx.x * 256 + threadIdx.x;
  if (i < NN * D) {
    float v = accum[i];
    out[i] = v > 0.f ? v : 0.01f * v;
  }
}

extern "C" void kernel_launch(void* const* d_in, const int* in_sizes, int n_in,
                              void* d_out, int out_size, void* d_ws, size_t ws_size,
                              hipStream_t stream) {
  const float* nodes  = (const float*)d_in[0];
  const int*   eidx   = (const int*)d_in[1];
  const float* efeat  = (const float*)d_in[2];
  const float* Wq     = (const float*)d_in[3];
  const float* bq     = (const float*)d_in[4];
  const float* W1     = (const float*)d_in[5];
  const float* b1     = (const float*)d_in[6];
  const float* gamma_ = (const float*)d_in[7];
  const float* beta_  = (const float*)d_in[8];
  const float* W2     = (const float*)d_in[9];
  const float* b2     = (const float*)d_in[10];
  const int* senders   = eidx;
  const int* receivers = eidx + NE;

  float* ws      = (float*)d_ws;
  float* logits  = ws;                 // NE
  float* exp_l   = ws + NE;            // NE
  float* seg_max = ws + 2 * NE;        // NN
  float* seg_sum = seg_max + NN;       // NN
  float* accum   = seg_sum + NN;       // NN*D

  hipMemsetAsync(seg_max, 0, NN * sizeof(float), stream);
  hipMemsetAsync(seg_sum, 0, NN * sizeof(float), stream);
  hipMemsetAsync(accum, 0, (size_t)NN * D * sizeof(float), stream);

  k_logits<<<NE / EPB, 256, 0, stream>>>(nodes, senders, receivers, efeat,
                                         W1, b1, gamma_, beta_, W2, b2,
                                         logits, seg_max);
  k_exp<<<(NE + 255) / 256, 256, 0, stream>>>(logits, receivers, seg_max,
                                              exp_l, seg_sum);
  k_scatter<<<NE / EPB, 256, 0, stream>>>(nodes, senders, receivers, efeat,
                                          Wq, bq, exp_l, seg_sum, accum);
  k_final<<<(NN * D + 255) / 256, 256, 0, stream>>>(accum, (float*)d_out);
}

// Round 2
// 738.529 us; speedup vs baseline: 4.0633x; 4.0633x over previous
//
#include <hip/hip_runtime.h>

#define NN 50000
#define NE 800000
#define D 128
#define ED 64
#define IN_DIM 320
#define MB 64            // edges per block
#define KP 328           // padded LDS row (ushorts)

typedef short short8 __attribute__((ext_vector_type(8)));
typedef float f32x4 __attribute__((ext_vector_type(4)));

__device__ __forceinline__ ushort f2b(float f) {
  uint u = __float_as_uint(f);
  return (ushort)((u + 0x7FFFu + ((u >> 16) & 1u)) >> 16);
}

__device__ __forceinline__ void st4(ushort* dst, float4 v) {
  ushort4 u; u.x = f2b(v.x); u.y = f2b(v.y); u.z = f2b(v.z); u.w = f2b(v.w);
  *reinterpret_cast<ushort4*>(dst) = u;
}

// stage 64 edges of x (bf16) into xs[e][k]; 4 threads per edge
__device__ __forceinline__ void stage_x(
    ushort xs[MB][KP], const int* __restrict__ senders,
    const int* __restrict__ receivers, const float* __restrict__ nodes,
    const float* __restrict__ efeat, int e0, int tid)
{
  const int e = tid >> 2, p = tid & 3;
  const float* ns = nodes + (size_t)senders[e0 + e] * D;
  const float* nr = nodes + (size_t)receivers[e0 + e] * D;
  const float* ef = efeat + (size_t)(e0 + e) * ED;
#pragma unroll
  for (int i = 0; i < 8; ++i) {
    int fi = p + 4 * i;
    st4(&xs[e][fi * 4], *(const float4*)(ns + fi * 4));
  }
#pragma unroll
  for (int i = 0; i < 8; ++i) {
    int fi = p + 4 * i;
    st4(&xs[e][128 + fi * 4], *(const float4*)(nr + fi * 4));
  }
#pragma unroll
  for (int i = 0; i < 4; ++i) {
    int fi = p + 4 * i;
    st4(&xs[e][256 + fi * 4], *(const float4*)(ef + fi * 4));
  }
}

// ---------------- weight transpose + bf16 convert ---------------------------
__global__ __launch_bounds__(256) void k_wconv(
    const float* __restrict__ Wq, const float* __restrict__ W1,
    ushort* __restrict__ Wqt, ushort* __restrict__ W1t)
{
  int i = blockIdx.x * 256 + threadIdx.x;   // over 128*320
  if (i < D * IN_DIM) {
    int n = i / IN_DIM, k = i - n * IN_DIM;
    Wqt[i] = f2b(Wq[k * D + n]);
    W1t[i] = f2b(W1[k * D + n]);
  }
}

// ---------------- pass 1: logits + segment max ------------------------------
__global__ __launch_bounds__(256) void k_logits(
    const float* __restrict__ nodes,
    const int* __restrict__ senders, const int* __restrict__ receivers,
    const float* __restrict__ efeat,
    const ushort* __restrict__ W1t, const float* __restrict__ b1,
    const float* __restrict__ gamma_, const float* __restrict__ beta_,
    const float* __restrict__ W2, const float* __restrict__ b2,
    float* __restrict__ logits, float* __restrict__ seg_max)
{
  __shared__ ushort xs[MB][KP];
  __shared__ int sR[MB];
  __shared__ float red[MB][4][2];
  __shared__ float fin[MB][2];
  __shared__ float dred[MB][4];
  const int tid = threadIdx.x;
  const int e0 = blockIdx.x * MB;

  if (tid < MB) sR[tid] = receivers[e0 + tid];
  stage_x(xs, senders, receivers, nodes, efeat, e0, tid);

  const int w = tid >> 6, l = tid & 63, lr = l & 15, lg = l >> 4;
  const int n0 = (2 * w) * 16 + lr, n1 = (2 * w + 1) * 16 + lr;

  // preload this wave's weight panel into registers (overlaps staging)
  short8 Bf[10][2];
#pragma unroll
  for (int ks = 0; ks < 10; ++ks) {
    Bf[ks][0] = *reinterpret_cast<const short8*>(W1t + n0 * IN_DIM + ks * 32 + lg * 8);
    Bf[ks][1] = *reinterpret_cast<const short8*>(W1t + n1 * IN_DIM + ks * 32 + lg * 8);
  }
  __syncthreads();

  f32x4 acc[4][2] = {};
#pragma unroll
  for (int ks = 0; ks < 10; ++ks) {
    short8 A[4];
#pragma unroll
    for (int mt = 0; mt < 4; ++mt)
      A[mt] = *reinterpret_cast<const short8*>(&xs[mt * 16 + lr][ks * 32 + lg * 8]);
#pragma unroll
    for (int mt = 0; mt < 4; ++mt)
#pragma unroll
      for (int nt = 0; nt < 2; ++nt)
        acc[mt][nt] = __builtin_amdgcn_mfma_f32_16x16x32_bf16(
            A[mt], Bf[ks][nt], acc[mt][nt], 0, 0, 0);
  }

  // bias + ReLU, then LN stats across 128 cols
  const float b1a = b1[n0], b1b = b1[n1];
#pragma unroll
  for (int mt = 0; mt < 4; ++mt)
#pragma unroll
    for (int r = 0; r < 4; ++r) {
      acc[mt][0][r] = fmaxf(acc[mt][0][r] + b1a, 0.f);
      acc[mt][1][r] = fmaxf(acc[mt][1][r] + b1b, 0.f);
    }
#pragma unroll
  for (int mt = 0; mt < 4; ++mt)
#pragma unroll
    for (int r = 0; r < 4; ++r) {
      float s = acc[mt][0][r] + acc[mt][1][r];
      float q = acc[mt][0][r] * acc[mt][0][r] + acc[mt][1][r] * acc[mt][1][r];
#pragma unroll
      for (int off = 1; off < 16; off <<= 1) {
        s += __shfl_xor(s, off);
        q += __shfl_xor(q, off);
      }
      if (lr == mt * 4 + r) {
        red[mt * 16 + lg * 4 + r][w][0] = s;
        red[mt * 16 + lg * 4 + r][w][1] = q;
      }
    }
  __syncthreads();
  if (tid < MB) {
    float s = red[tid][0][0] + red[tid][1][0] + red[tid][2][0] + red[tid][3][0];
    float q = red[tid][0][1] + red[tid][1][1] + red[tid][2][1] + red[tid][3][1];
    float mu = s * (1.f / 128.f);
    float var = fmaxf(q * (1.f / 128.f) - mu * mu, 0.f);
    fin[tid][0] = mu;
    fin[tid][1] = rsqrtf(var + 1e-5f);
  }
  __syncthreads();

  const float g0 = gamma_[n0], g1 = gamma_[n1];
  const float be0 = beta_[n0], be1 = beta_[n1];
  const float w20 = W2[n0], w21 = W2[n1];
#pragma unroll
  for (int mt = 0; mt < 4; ++mt)
#pragma unroll
    for (int r = 0; r < 4; ++r) {
      int row = mt * 16 + lg * 4 + r;
      float mu = fin[row][0], rs = fin[row][1];
      float h0 = (acc[mt][0][r] - mu) * rs * g0 + be0;
      float h1 = (acc[mt][1][r] - mu) * rs * g1 + be1;
      float dv = h0 * w20 + h1 * w21;
#pragma unroll
      for (int off = 1; off < 16; off <<= 1) dv += __shfl_xor(dv, off);
      if (lr == mt * 4 + r) dred[row][w] = dv;
    }
  __syncthreads();
  if (tid < MB) {
    float dv = dred[tid][0] + dred[tid][1] + dred[tid][2] + dred[tid][3] + b2[0];
    float logit = fmaxf(dv, 0.f);
    logits[e0 + tid] = logit;
    atomicMax((int*)&seg_max[sR[tid]], __float_as_int(logit));
  }
}

// ---------------- pass 2: exp + segment sum ---------------------------------
__global__ __launch_bounds__(256) void k_exp(
    const float* __restrict__ logits, const int* __restrict__ receivers,
    const float* __restrict__ seg_max, float* __restrict__ exp_l,
    float* __restrict__ seg_sum)
{
  int i = blockIdx.x * 256 + threadIdx.x;
  if (i < NE) {
    int r = receivers[i];
    float ex = expf(logits[i] - seg_max[r]);
    exp_l[i] = ex;
    atomicAdd(&seg_sum[r], ex);
  }
}

// ---------------- pass 3: queries * weight, scatter-add ---------------------
__global__ __launch_bounds__(256) void k_scatter(
    const float* __restrict__ nodes,
    const int* __restrict__ senders, const int* __restrict__ receivers,
    const float* __restrict__ efeat,
    const ushort* __restrict__ Wqt, const float* __restrict__ bq,
    const float* __restrict__ exp_l, const float* __restrict__ seg_sum,
    float* __restrict__ accum)
{
  __shared__ ushort xs[MB][KP];
  __shared__ float wrow[MB];
  __shared__ int rr[MB];
  const int tid = threadIdx.x;
  const int e0 = blockIdx.x * MB;

  if (tid < MB) {
    int r = receivers[e0 + tid];
    rr[tid] = r;
    wrow[tid] = exp_l[e0 + tid] / (seg_sum[r] + 1e-10f);
  }
  stage_x(xs, senders, receivers, nodes, efeat, e0, tid);

  const int w = tid >> 6, l = tid & 63, lr = l & 15, lg = l >> 4;
  const int n0 = (2 * w) * 16 + lr, n1 = (2 * w + 1) * 16 + lr;

  short8 Bf[10][2];
#pragma unroll
  for (int ks = 0; ks < 10; ++ks) {
    Bf[ks][0] = *reinterpret_cast<const short8*>(Wqt + n0 * IN_DIM + ks * 32 + lg * 8);
    Bf[ks][1] = *reinterpret_cast<const short8*>(Wqt + n1 * IN_DIM + ks * 32 + lg * 8);
  }
  __syncthreads();

  f32x4 acc[4][2] = {};
#pragma unroll
  for (int ks = 0; ks < 10; ++ks) {
    short8 A[4];
#pragma unroll
    for (int mt = 0; mt < 4; ++mt)
      A[mt] = *reinterpret_cast<const short8*>(&xs[mt * 16 + lr][ks * 32 + lg * 8]);
#pragma unroll
    for (int mt = 0; mt < 4; ++mt)
#pragma unroll
      for (int nt = 0; nt < 2; ++nt)
        acc[mt][nt] = __builtin_amdgcn_mfma_f32_16x16x32_bf16(
            A[mt], Bf[ks][nt], acc[mt][nt], 0, 0, 0);
  }

  const float bq0 = bq[n0], bq1 = bq[n1];
#pragma unroll
  for (int mt = 0; mt < 4; ++mt)
#pragma unroll
    for (int r = 0; r < 4; ++r) {
      int row = mt * 16 + lg * 4 + r;
      float wt_ = wrow[row];
      size_t base = (size_t)rr[row] * D;
      atomicAdd(&accum[base + n0], (acc[mt][0][r] + bq0) * wt_);
      atomicAdd(&accum[base + n1], (acc[mt][1][r] + bq1) * wt_);
    }
}

// ---------------- pass 4: leaky relu ----------------------------------------
__global__ __launch_bounds__(256) void k_final(
    const float* __restrict__ accum, float* __restrict__ out)
{
  int i = blockIdx.x * 256 + threadIdx.x;
  if (i < NN * D) {
    float v = accum[i];
    out[i] = v > 0.f ? v : 0.01f * v;
  }
}

extern "C" void kernel_launch(void* const* d_in, const int* in_sizes, int n_in,
                              void* d_out, int out_size, void* d_ws, size_t ws_size,
                              hipStream_t stream) {
  const float* nodes  = (const float*)d_in[0];
  const int*   eidx   = (const int*)d_in[1];
  const float* efeat  = (const float*)d_in[2];
  const float* Wq     = (const float*)d_in[3];
  const float* bq     = (const float*)d_in[4];
  const float* W1     = (const float*)d_in[5];
  const float* b1     = (const float*)d_in[6];
  const float* gamma_ = (const float*)d_in[7];
  const float* beta_  = (const float*)d_in[8];
  const float* W2     = (const float*)d_in[9];
  const float* b2     = (const float*)d_in[10];
  const int* senders   = eidx;
  const int* receivers = eidx + NE;

  float* ws      = (float*)d_ws;
  float* logits  = ws;                  // NE
  float* exp_l   = ws + NE;             // NE
  float* seg_max = ws + 2 * NE;         // NN
  float* seg_sum = seg_max + NN;        // NN
  float* accum   = seg_sum + NN;        // NN*D
  ushort* Wqt    = (ushort*)(accum + (size_t)NN * D);  // 128*320
  ushort* W1t    = Wqt + D * IN_DIM;                   // 128*320

  hipMemsetAsync(seg_max, 0, NN * sizeof(float), stream);
  hipMemsetAsync(seg_sum, 0, NN * sizeof(float), stream);
  hipMemsetAsync(accum, 0, (size_t)NN * D * sizeof(float), stream);

  k_wconv<<<(D * IN_DIM + 255) / 256, 256, 0, stream>>>(Wq, W1, Wqt, W1t);
  k_logits<<<NE / MB, 256, 0, stream>>>(nodes, senders, receivers, efeat,
                                        W1t, b1, gamma_, beta_, W2, b2,
                                        logits, seg_max);
  k_exp<<<(NE + 255) / 256, 256, 0, stream>>>(logits, receivers, seg_max,
                                              exp_l, seg_sum);
  k_scatter<<<NE / MB, 256, 0, stream>>>(nodes, senders, receivers, efeat,
                                         Wqt, bq, exp_l, seg_sum, accum);
  k_final<<<(NN * D + 255) / 256, 256, 0, stream>>>(accum, (float*)d_out);
}